// Round 2
// baseline (401.454 us; speedup 1.0000x reference)
//
#include <hip/hip_runtime.h>

#define Bn 8
#define Cn 256
#define Hn 128
#define Wn 128
// H*W = 16384 = 1<<14; W = 1<<7

// ---------------- Kernel 1: offset conv, occupancy-split ----------------
// Block = 256 threads = 64 pixels x 4 channel-chunks (64 ch each).
// LDS reduction of the 4 partial sums per pixel, then fold into bilinear
// weights + base gather index. 2048 blocks -> 8 blocks/CU -> 32 waves/CU.
#define CCH 4            // channel chunks per pixel
#define CPC (Cn / CCH)   // 64 channels per chunk

__global__ __launch_bounds__(256) void conv_offset_kernel(
    const float* __restrict__ x, const float* __restrict__ wconv,
    const float* __restrict__ bconv, float4* __restrict__ wts,
    int* __restrict__ basei)
{
    __shared__ float s0[CCH][64];
    __shared__ float s1[CCH][64];

    const int lane  = threadIdx.x & 63;
    const int chunk = threadIdx.x >> 6;
    const int gid   = blockIdx.x * 64 + lane;   // pixel id 0..B*H*W-1
    const int w = gid & (Wn - 1);
    const int h = (gid >> 7) & (Hn - 1);
    const int b = gid >> 14;

    const float* xb = x + (size_t)b * Cn * Hn * Wn
                        + (size_t)chunk * CPC * Hn * Wn + h * Wn + w;

    const bool hm = (h > 0), hp = (h < Hn - 1);
    const bool wm = (w > 0), wp = (w < Wn - 1);

    float acc0 = 0.f, acc1 = 0.f;
    const float* w0b = wconv + chunk * CPC * 9;
    const float* w1b = wconv + Cn * 9 + chunk * CPC * 9;

    #pragma unroll 4
    for (int c = 0; c < CPC; ++c) {
        const float* xc = xb + c * (Hn * Wn);
        float v00 = (hm && wm) ? xc[-Wn - 1] : 0.f;
        float v01 = (hm)       ? xc[-Wn]     : 0.f;
        float v02 = (hm && wp) ? xc[-Wn + 1] : 0.f;
        float v10 = (wm)       ? xc[-1]      : 0.f;
        float v11 =              xc[0];
        float v12 = (wp)       ? xc[1]       : 0.f;
        float v20 = (hp && wm) ? xc[Wn - 1]  : 0.f;
        float v21 = (hp)       ? xc[Wn]      : 0.f;
        float v22 = (hp && wp) ? xc[Wn + 1]  : 0.f;

        const float* w0 = w0b + c * 9;   // lane-uniform -> s_load
        const float* w1 = w1b + c * 9;
        acc0 = fmaf(v00, w0[0], acc0); acc0 = fmaf(v01, w0[1], acc0);
        acc0 = fmaf(v02, w0[2], acc0); acc0 = fmaf(v10, w0[3], acc0);
        acc0 = fmaf(v11, w0[4], acc0); acc0 = fmaf(v12, w0[5], acc0);
        acc0 = fmaf(v20, w0[6], acc0); acc0 = fmaf(v21, w0[7], acc0);
        acc0 = fmaf(v22, w0[8], acc0);
        acc1 = fmaf(v00, w1[0], acc1); acc1 = fmaf(v01, w1[1], acc1);
        acc1 = fmaf(v02, w1[2], acc1); acc1 = fmaf(v10, w1[3], acc1);
        acc1 = fmaf(v11, w1[4], acc1); acc1 = fmaf(v12, w1[5], acc1);
        acc1 = fmaf(v20, w1[6], acc1); acc1 = fmaf(v21, w1[7], acc1);
        acc1 = fmaf(v22, w1[8], acc1);
    }

    s0[chunk][lane] = acc0;
    s1[chunk][lane] = acc1;
    __syncthreads();

    if (chunk == 0) {
        acc0 += s0[1][lane] + s0[2][lane] + s0[3][lane] + bconv[0];
        acc1 += s1[1][lane] + s1[2][lane] + s1[3][lane] + bconv[1];

        float px = (float)h + acc0;
        float py = (float)w + acc1;
        px = fminf(fmaxf(px, 0.f), (float)(Hn - 2));
        py = fminf(fmaxf(py, 0.f), (float)(Wn - 2));
        float fx = floorf(px), fy = floorf(py);
        float dx = px - fx, dy = py - fy;
        int qx0 = (int)fx, qy0 = (int)fy;

        float4 g;
        g.x = (1.f - dx) * (1.f - dy);   // lt
        g.y = dx * dy;                   // rb
        g.z = (1.f - dx) * dy;           // lb
        g.w = dx * (1.f - dy);           // rt
        wts[gid] = g;
        basei[gid] = qx0 * Wn + qy0;
    }
}

// ---------------- Kernel 2: bilinear gather, occupancy-split ----------------
// One thread per (pixel, 32-channel chunk): 1M threads, 4096 blocks.
// hw in the low bits keeps loads/stores lane-coalesced.
#define SCH 8             // sample channel chunks
#define SPC (Cn / SCH)    // 32 channels per thread

__global__ __launch_bounds__(256) void sample_kernel(
    const float* __restrict__ x, const float4* __restrict__ wts,
    const int* __restrict__ basei, float* __restrict__ out)
{
    const int tid = blockIdx.x * 256 + threadIdx.x;
    const int hw = tid & (Hn * Wn - 1);
    const int r  = tid >> 14;
    const int chunk = r & (SCH - 1);
    const int b = r >> 3;
    const int gid = (b << 14) | hw;

    const float4 g = wts[gid];
    const int bs = basei[gid];

    const float* xb = x + (size_t)b * Cn * Hn * Wn
                        + (size_t)chunk * SPC * Hn * Wn + bs;
    float* ob = out + (size_t)b * Cn * Hn * Wn
                    + (size_t)chunk * SPC * Hn * Wn + hw;

    #pragma unroll 8
    for (int c = 0; c < SPC; ++c) {
        const float* xc = xb + c * (Hn * Wn);
        float lt = xc[0];
        float lb = xc[1];
        float rt = xc[Wn];
        float rb = xc[Wn + 1];
        float v = g.x * lt + g.y * rb + g.z * lb + g.w * rt;
        __builtin_nontemporal_store(v, ob + c * (Hn * Wn));
    }
}

extern "C" void kernel_launch(void* const* d_in, const int* in_sizes, int n_in,
                              void* d_out, int out_size, void* d_ws, size_t ws_size,
                              hipStream_t stream) {
    const float* x     = (const float*)d_in[0];
    const float* wconv = (const float*)d_in[1];
    const float* bconv = (const float*)d_in[2];
    float* out = (float*)d_out;

    const int npix = Bn * Hn * Wn;  // 131072
    float4* wts  = (float4*)d_ws;
    int*    basei = (int*)((char*)d_ws + (size_t)npix * sizeof(float4));

    conv_offset_kernel<<<npix / 64, 256, 0, stream>>>(x, wconv, bconv, wts, basei);
    sample_kernel<<<(npix * SCH) / 256, 256, 0, stream>>>(x, wts, basei, out);
}

// Round 3
// 338.293 us; speedup vs baseline: 1.1867x; 1.1867x over previous
//
#include <hip/hip_runtime.h>

#define Bn 8
#define Cn 256
#define Hn 128
#define Wn 128
#define NPIX (Bn * Hn * Wn)   // 131072
// H*W = 16384 = 1<<14; W = 1<<7

// ---------------- Kernel 1: offset conv partials ----------------
// v1 geometry (proven lowest fetch + VGPR=40): block = 256 threads = 256
// contiguous pixels = 2 full rows, 1 thread/pixel. Channel split 4x ACROSS
// blocks (disjoint channel slices -> no fetch amplification). Partial sums
// written to ws (full overwrite, no atomics/memset). 2048 blocks ->
// 8 blocks/CU; launch_bounds(256,8) pins VGPR<=64 for 8 waves/SIMD.
#define CCH 4            // channel chunks
#define CPC (Cn / CCH)   // 64 channels per chunk

__global__ __launch_bounds__(256, 8) void conv_partial_kernel(
    const float* __restrict__ x, const float* __restrict__ wconv,
    float2* __restrict__ part)
{
    const int pg    = blockIdx.x & 511;   // pixel group (low bits: adjacent
    const int chunk = blockIdx.x >> 9;    // blocks share halo rows in time)
    const int gid = pg * 256 + threadIdx.x;
    const int w = gid & (Wn - 1);
    const int h = (gid >> 7) & (Hn - 1);
    const int b = gid >> 14;

    const float* xb = x + ((size_t)b * Cn + chunk * CPC) * (Hn * Wn) + h * Wn + w;

    const bool hm = (h > 0), hp = (h < Hn - 1);
    const bool wm = (w > 0), wp = (w < Wn - 1);

    float acc0 = 0.f, acc1 = 0.f;
    const float* w0b = wconv + chunk * CPC * 9;
    const float* w1b = wconv + Cn * 9 + chunk * CPC * 9;

    #pragma unroll 2
    for (int c = 0; c < CPC; ++c) {
        const float* xc = xb + c * (Hn * Wn);
        float v00 = (hm && wm) ? xc[-Wn - 1] : 0.f;
        float v01 = (hm)       ? xc[-Wn]     : 0.f;
        float v02 = (hm && wp) ? xc[-Wn + 1] : 0.f;
        float v10 = (wm)       ? xc[-1]      : 0.f;
        float v11 =              xc[0];
        float v12 = (wp)       ? xc[1]       : 0.f;
        float v20 = (hp && wm) ? xc[Wn - 1]  : 0.f;
        float v21 = (hp)       ? xc[Wn]      : 0.f;
        float v22 = (hp && wp) ? xc[Wn + 1]  : 0.f;

        const float* w0 = w0b + c * 9;   // lane-uniform -> s_load
        const float* w1 = w1b + c * 9;
        acc0 = fmaf(v00, w0[0], acc0); acc0 = fmaf(v01, w0[1], acc0);
        acc0 = fmaf(v02, w0[2], acc0); acc0 = fmaf(v10, w0[3], acc0);
        acc0 = fmaf(v11, w0[4], acc0); acc0 = fmaf(v12, w0[5], acc0);
        acc0 = fmaf(v20, w0[6], acc0); acc0 = fmaf(v21, w0[7], acc0);
        acc0 = fmaf(v22, w0[8], acc0);
        acc1 = fmaf(v00, w1[0], acc1); acc1 = fmaf(v01, w1[1], acc1);
        acc1 = fmaf(v02, w1[2], acc1); acc1 = fmaf(v10, w1[3], acc1);
        acc1 = fmaf(v11, w1[4], acc1); acc1 = fmaf(v12, w1[5], acc1);
        acc1 = fmaf(v20, w1[6], acc1); acc1 = fmaf(v21, w1[7], acc1);
        acc1 = fmaf(v22, w1[8], acc1);
    }

    part[(size_t)chunk * NPIX + gid] = make_float2(acc0, acc1);
}

// ---------------- Kernel 2: bilinear gather ----------------
// One thread per (pixel, 32-channel chunk): 1M threads, 4096 blocks,
// 16 blocks/CU. Sums the 4 conv partials (L2/L3-resident, 4 MB), computes
// bilinear weights in-thread, then gathers with coalesced stores.
#define SCH 8             // sample channel chunks
#define SPC (Cn / SCH)    // 32 channels per thread

__global__ __launch_bounds__(256, 8) void sample_kernel(
    const float* __restrict__ x, const float2* __restrict__ part,
    const float* __restrict__ bconv, float* __restrict__ out)
{
    const int tid = blockIdx.x * 256 + threadIdx.x;
    const int hw = tid & (Hn * Wn - 1);
    const int r  = tid >> 14;
    const int chunk = r & (SCH - 1);
    const int b = r >> 3;
    const int gid = (b << 14) | hw;
    const int w = hw & (Wn - 1);
    const int h = hw >> 7;

    float2 p0 = part[gid];
    float2 p1 = part[NPIX + gid];
    float2 p2 = part[2 * NPIX + gid];
    float2 p3 = part[3 * NPIX + gid];
    float off0 = p0.x + p1.x + p2.x + p3.x + bconv[0];
    float off1 = p0.y + p1.y + p2.y + p3.y + bconv[1];

    float px = (float)h + off0;
    float py = (float)w + off1;
    px = fminf(fmaxf(px, 0.f), (float)(Hn - 2));
    py = fminf(fmaxf(py, 0.f), (float)(Wn - 2));
    float fx = floorf(px), fy = floorf(py);
    float dx = px - fx, dy = py - fy;
    int bs = (int)fx * Wn + (int)fy;

    float glt = (1.f - dx) * (1.f - dy);
    float grb = dx * dy;
    float glb = (1.f - dx) * dy;
    float grt = dx * (1.f - dy);

    const float* xb = x + ((size_t)b * Cn + chunk * SPC) * (Hn * Wn) + bs;
    float* ob = out + ((size_t)b * Cn + chunk * SPC) * (Hn * Wn) + hw;

    #pragma unroll 8
    for (int c = 0; c < SPC; ++c) {
        const float* xc = xb + c * (Hn * Wn);
        float lt = xc[0];
        float lb = xc[1];
        float rt = xc[Wn];
        float rb = xc[Wn + 1];
        float v = glt * lt + grb * rb + glb * lb + grt * rt;
        __builtin_nontemporal_store(v, ob + c * (Hn * Wn));
    }
}

extern "C" void kernel_launch(void* const* d_in, const int* in_sizes, int n_in,
                              void* d_out, int out_size, void* d_ws, size_t ws_size,
                              hipStream_t stream) {
    const float* x     = (const float*)d_in[0];
    const float* wconv = (const float*)d_in[1];
    const float* bconv = (const float*)d_in[2];
    float* out = (float*)d_out;

    float2* part = (float2*)d_ws;   // 4 chunks x 131072 x float2 = 4 MB

    conv_partial_kernel<<<(NPIX / 256) * CCH, 256, 0, stream>>>(x, wconv, part);
    sample_kernel<<<(NPIX * SCH) / 256, 256, 0, stream>>>(x, part, bconv, out);
}